// Round 7
// baseline (412.106 us; speedup 1.0000x reference)
//
#include <hip/hip_runtime.h>
#include <hip/hip_bf16.h>

#define NN 8192
#define DD 128

typedef __attribute__((ext_vector_type(8))) short short8;
typedef __attribute__((ext_vector_type(4))) float f32x4;
typedef __attribute__((ext_vector_type(4))) int i32x4;
typedef unsigned int u32;

__device__ __forceinline__ ushort f2bf(float f) {
    __hip_bfloat16 h = __float2bfloat16(f);
    return *(ushort*)&h;
}

// async 16B/lane global->LDS; LDS dest must be wave-uniform base + lane*16.
__device__ __forceinline__ void async_ld16(const void* g, void* l) {
    __builtin_amdgcn_global_load_lds(
        (const __attribute__((address_space(1))) u32*)g,
        (__attribute__((address_space(3))) u32*)l, 16, 0, 0);
}

// ---------------- K12: Wh = X @ Ws fused with per-row scalars + bf16 transpose ----
// 256 blocks x 256 thr; 32 rows/block; 4x4 register tile per thread.
// At end of k-loop each thread's acc holds Wh[r0..r0+3][c0..c0+3]; reduce
// across the 32 threads of a row-group for s1/s2 (shfl), and emit WhT bf16
// through an 8KB LDS transpose tile. Wh fp32 never touches HBM.
__global__ __launch_bounds__(256) void k12_gemm(const float* __restrict__ X,
                                                const float* __restrict__ Ws,
                                                const float* __restrict__ a,
                                                ushort* __restrict__ WhT,
                                                float* __restrict__ C1,
                                                float* __restrict__ C1s,
                                                float2* __restrict__ E2) {
    __shared__ float lWs[128 * 132];   // [k][c] pad 132
    __shared__ float lX[32 * 132];     // [r][c] pad 132
    __shared__ ushort lT2[128 * 32];   // [c][r] bf16 transpose staging
    __shared__ float la[256];
    int t = threadIdx.x, bx = blockIdx.x;
    la[t] = a[t];
    const float4* Ws4 = (const float4*)Ws;
    const float4* X4 = (const float4*)X;
    for (int j = 0; j < 16; ++j) {
        int u = j * 256 + t;           // 0..4095 float4s of Ws
        int k = u >> 5, c4 = u & 31;
        *(float4*)&lWs[k * 132 + c4 * 4] = Ws4[u];
    }
    for (int j = 0; j < 4; ++j) {
        int u = j * 256 + t;           // 0..1023 float4s of X tile
        int r = u >> 5, c4 = u & 31;
        *(float4*)&lX[r * 132 + c4 * 4] = X4[bx * 1024 + u];
    }
    __syncthreads();
    int r0 = (t >> 5) * 4, c0 = (t & 31) * 4;
    float acc[4][4];
#pragma unroll
    for (int i = 0; i < 4; ++i)
#pragma unroll
        for (int j = 0; j < 4; ++j) acc[i][j] = 0.f;
#pragma unroll 4
    for (int k = 0; k < 128; ++k) {
        float4 wv = *(const float4*)&lWs[k * 132 + c0];
        float x0 = lX[(r0 + 0) * 132 + k];
        float x1 = lX[(r0 + 1) * 132 + k];
        float x2 = lX[(r0 + 2) * 132 + k];
        float x3 = lX[(r0 + 3) * 132 + k];
#pragma unroll
        for (int j = 0; j < 4; ++j) {
            acc[0][j] += x0 * ((const float*)&wv)[j];
            acc[1][j] += x1 * ((const float*)&wv)[j];
            acc[2][j] += x2 * ((const float*)&wv)[j];
            acc[3][j] += x3 * ((const float*)&wv)[j];
        }
    }
    // bf16 transpose staging
#pragma unroll
    for (int i = 0; i < 4; ++i)
#pragma unroll
        for (int j = 0; j < 4; ++j)
            lT2[(c0 + j) * 32 + r0 + i] = f2bf(acc[i][j]);
    // per-row scalars: s1 = Wh[r].a1, s2 = Wh[r].a2
    float p1[4], p2[4];
#pragma unroll
    for (int i = 0; i < 4; ++i) {
        p1[i] = 0.f; p2[i] = 0.f;
#pragma unroll
        for (int j = 0; j < 4; ++j) {
            p1[i] += acc[i][j] * la[c0 + j];
            p2[i] += acc[i][j] * la[128 + c0 + j];
        }
    }
#pragma unroll
    for (int m = 1; m < 32; m <<= 1) {
#pragma unroll
        for (int i = 0; i < 4; ++i) {
            p1[i] += __shfl_xor(p1[i], m);
            p2[i] += __shfl_xor(p2[i], m);
        }
    }
    if ((t & 31) == 0) {
#pragma unroll
        for (int i = 0; i < 4; ++i) {
            int row = bx * 32 + r0 + i;
            C1[row]  = __expf(p1[i]);
            C1s[row] = __expf(0.2f * p1[i]);
            E2[row]  = make_float2(__expf(p2[i]), __expf(0.2f * p2[i]));
        }
    }
    __syncthreads();
    // WhT[d][srcrow]: thread t -> d=t>>1, half=t&1; 32B contiguous
    {
        int d = t >> 1, hf = t & 1;
        uint4* dst = (uint4*)&WhT[(size_t)d * NN + bx * 32 + hf * 16];
        const uint4* src = (const uint4*)&lT2[d * 32 + hf * 16];
        dst[0] = src[0];
        dst[1] = src[1];
    }
}

// ---------------- K3: masked-softmax GEMM, barrier-free main loop ----------------
// grid (32 rowblocks, 16 ksplit) x 512 thr (8 waves x 32 rows = 256 rows/block).
// The ENTIRE per-ksplit B-slice (512k x 128d bf16 = 128 KB) + E-slice (4 KB)
// is staged into LDS ONCE (one barrier); the kt-loop then has ZERO barriers:
// each wave streams its A rows (nontemporal, depth-1 register prefetch),
// builds the exp-weight af once per (row,k), ds_reads resident B fragments,
// and accumulates via MFMA. No vmcnt(0) drains in the loop -- each wave waits
// only on its OWN A loads, issued a full kt (~1000 cyc) earlier.
// Row sums via MFMA against all-ones B. Split-K partials; NO atomics.
#define PACK4(b, v, sh)                                     \
    b |= (u32)((v).x & 1) << (sh);                          \
    b |= (u32)((v).y & 1) << ((sh) + 1);                    \
    b |= (u32)((v).z & 1) << ((sh) + 2);                    \
    b |= (u32)((v).w & 1) << ((sh) + 3);

__global__ __launch_bounds__(512, 2) void k3_main(
    const int* __restrict__ A, const ushort* __restrict__ WhT,
    const float* __restrict__ C1, const float* __restrict__ C1s,
    const float2* __restrict__ E2,
    float* __restrict__ Hp, float* __restrict__ Lp) {

    __shared__ __align__(16) char lB[131072];  // [p = kt*16+tp*8+c][lane*16]
    __shared__ __align__(16) char lE[4096];    // float2 E for 512 k

    int tid = threadIdx.x;
    int lane = tid & 63;
    int w = tid >> 6;           // 8 waves
    int n = lane & 15;
    int kg = lane >> 4;

    int bx = blockIdx.x;        // 32 row-blocks (256 rows each)
    int kb = blockIdx.y;        // 16 k-splits (512 k each)
    int rb = bx * 256 + w * 32; // wave's 32 rows (two 16-row groups)

    float c1_0 = C1[rb + n],      c1s_0 = C1s[rb + n];
    float c1_1 = C1[rb + 16 + n], c1s_1 = C1s[rb + 16 + n];

    const int* pA0 = A + (size_t)(rb + n) * NN + (size_t)kb * 512 + kg * 8;
    const int* pA1 = pA0 + (size_t)16 * NN;

    i32x4 ar[8];                // [grp*4 + tp*2 + half], one tile ahead
    u32 a_cur0, a_cur1;

    // A tile 0 -> regs (issued first so its vmcnt-wait doesn't drain the DMAs)
#pragma unroll
    for (int tp = 0; tp < 2; ++tp) {
        ar[tp * 2 + 0]     = __builtin_nontemporal_load((const i32x4*)(pA0 + tp * 32));
        ar[tp * 2 + 1]     = __builtin_nontemporal_load((const i32x4*)(pA0 + tp * 32 + 4));
        ar[4 + tp * 2 + 0] = __builtin_nontemporal_load((const i32x4*)(pA1 + tp * 32));
        ar[4 + tp * 2 + 1] = __builtin_nontemporal_load((const i32x4*)(pA1 + tp * 32 + 4));
    }

    // stage ENTIRE B-slice (128 fragments x 1 KB) -- wave w stages p = w+8i
#pragma unroll
    for (int i = 0; i < 16; ++i) {
        int p = w + i * 8;
        int kt = p >> 4, tp = (p >> 3) & 1, c = p & 7;
        const ushort* src = WhT + (size_t)(c * 16 + n) * NN +
                            (size_t)kb * 512 + kt * 64 + tp * 32 + kg * 8;
        async_ld16(src, lB + p * 1024 + lane * 16);
    }
    if (w == 0)
#pragma unroll
        for (int i = 0; i < 4; ++i)
            async_ld16((const char*)(E2 + (size_t)kb * 512) + (i * 64 + lane) * 16,
                       lE + (i * 64 + lane) * 16);

    {
        u32 b0 = 0, b1 = 0;
#pragma unroll
        for (int tp = 0; tp < 2; ++tp) {
            PACK4(b0, ar[tp * 2 + 0], tp * 8);
            PACK4(b0, ar[tp * 2 + 1], tp * 8 + 4);
            PACK4(b1, ar[4 + tp * 2 + 0], tp * 8);
            PACK4(b1, ar[4 + tp * 2 + 1], tp * 8 + 4);
        }
        a_cur0 = b0; a_cur1 = b1;
    }

    short8 ones;
#pragma unroll
    for (int j = 0; j < 8; ++j) ones[j] = (short)0x3F80;  // bf16 1.0

    f32x4 acc0[8], acc1[8];
#pragma unroll
    for (int c = 0; c < 8; ++c) {
        acc0[c] = (f32x4){0.f, 0.f, 0.f, 0.f};
        acc1[c] = (f32x4){0.f, 0.f, 0.f, 0.f};
    }
    f32x4 accl0 = (f32x4){0.f, 0.f, 0.f, 0.f};
    f32x4 accl1 = (f32x4){0.f, 0.f, 0.f, 0.f};

    __syncthreads();   // the ONLY barrier: B/E LDS now resident + read-only

    for (int kt = 0; kt < 8; ++kt) {   // 8 x 64-k tiles, NO barriers
        if (kt < 7) {
            // prefetch next A tile (consumed at pack below)
#pragma unroll
            for (int tp = 0; tp < 2; ++tp) {
                ar[tp * 2 + 0]     = __builtin_nontemporal_load((const i32x4*)(pA0 + (kt + 1) * 64 + tp * 32));
                ar[tp * 2 + 1]     = __builtin_nontemporal_load((const i32x4*)(pA0 + (kt + 1) * 64 + tp * 32 + 4));
                ar[4 + tp * 2 + 0] = __builtin_nontemporal_load((const i32x4*)(pA1 + (kt + 1) * 64 + tp * 32));
                ar[4 + tp * 2 + 1] = __builtin_nontemporal_load((const i32x4*)(pA1 + (kt + 1) * 64 + tp * 32 + 4));
            }
        }
#pragma unroll
        for (int tp = 0; tp < 2; ++tp) {
            // 8 (ep,en) pairs for this lane's 8 k-slots (broadcast across n)
            const float4* ev = (const float4*)((const float*)lE +
                                               (kt * 64 + tp * 32 + kg * 8) * 2);
            float pe[16];
            *(float4*)(pe + 0)  = ev[0];
            *(float4*)(pe + 4)  = ev[1];
            *(float4*)(pe + 8)  = ev[2];
            *(float4*)(pe + 12) = ev[3];
            u32 ab0 = (a_cur0 >> (tp * 8)) & 0xffu;
            u32 ab1 = (a_cur1 >> (tp * 8)) & 0xffu;
            short8 af0, af1;
#pragma unroll
            for (int u = 0; u < 8; ++u) {
                // exp(leaky(s1+s2)) = max(e^s1 e^s2, e^.2s1 e^.2s2)
                float w0 = fmaxf(c1_0 * pe[2 * u], c1s_0 * pe[2 * u + 1]);
                float w1 = fmaxf(c1_1 * pe[2 * u], c1s_1 * pe[2 * u + 1]);
                af0[u] = ((ab0 >> u) & 1u) ? (short)f2bf(w0) : (short)0;
                af1[u] = ((ab1 >> u) & 1u) ? (short)f2bf(w1) : (short)0;
            }
            const short8* bb = (const short8*)(lB + (kt * 16 + tp * 8) * 1024);
#pragma unroll
            for (int c = 0; c < 8; ++c) {
                short8 bf = bb[c * 64 + lane];   // read ONCE, feed two MFMAs
                acc0[c] = __builtin_amdgcn_mfma_f32_16x16x32_bf16(af0, bf, acc0[c], 0, 0, 0);
                acc1[c] = __builtin_amdgcn_mfma_f32_16x16x32_bf16(af1, bf, acc1[c], 0, 0, 0);
            }
            accl0 = __builtin_amdgcn_mfma_f32_16x16x32_bf16(af0, ones, accl0, 0, 0, 0);
            accl1 = __builtin_amdgcn_mfma_f32_16x16x32_bf16(af1, ones, accl1, 0, 0, 0);
        }
        if (kt < 7) {   // pack next tile's masks (waits only this wave's A loads)
            u32 b0 = 0, b1 = 0;
#pragma unroll
            for (int tp = 0; tp < 2; ++tp) {
                PACK4(b0, ar[tp * 2 + 0], tp * 8);
                PACK4(b0, ar[tp * 2 + 1], tp * 8 + 4);
                PACK4(b1, ar[4 + tp * 2 + 0], tp * 8);
                PACK4(b1, ar[4 + tp * 2 + 1], tp * 8 + 4);
            }
            a_cur0 = b0; a_cur1 = b1;
        }
    }

    // epilogue. C/D layout: col = lane&15, row = (lane>>4)*4 + reg  [m89]
    float* Hpb = Hp + (size_t)kb * (NN * DD);
#pragma unroll
    for (int c = 0; c < 8; ++c)
#pragma unroll
        for (int r = 0; r < 4; ++r) {
            Hpb[(size_t)(rb + kg * 4 + r) * DD + c * 16 + n]      = acc0[c][r];
            Hpb[(size_t)(rb + 16 + kg * 4 + r) * DD + c * 16 + n] = acc1[c][r];
        }
    if (n == 0) {
        float* Lpb = Lp + (size_t)kb * NN;
#pragma unroll
        for (int r = 0; r < 4; ++r) {
            Lpb[rb + kg * 4 + r]      = accl0[r];
            Lpb[rb + 16 + kg * 4 + r] = accl1[r];
        }
    }
}

// ---------------- K4: combine split-K partials, normalize (float4) ----------------
// 262144 float4s total: 1024 blocks x 256 thr.
__global__ void k4_final(const float* __restrict__ Hp, const float* __restrict__ Lp,
                         float* __restrict__ out) {
    int g = blockIdx.x * 256 + threadIdx.x;   // 0..262143 float4s
    int i = g >> 5;                            // row (128 f / 4 = 32 f4 per row)
    float4 sv = make_float4(0.f, 0.f, 0.f, 0.f);
    float l = 0.f;
#pragma unroll
    for (int kb = 0; kb < 16; ++kb) {
        float4 v = *(const float4*)(Hp + (size_t)kb * (NN * DD) + (size_t)g * 4);
        sv.x += v.x; sv.y += v.y; sv.z += v.z; sv.w += v.w;
        l += Lp[(size_t)kb * NN + i];
    }
    float r = 1.f / l;
    *(float4*)(out + (size_t)g * 4) = make_float4(sv.x * r, sv.y * r, sv.z * r, sv.w * r);
}

extern "C" void kernel_launch(void* const* d_in, const int* in_sizes, int n_in,
                              void* d_out, int out_size, void* d_ws, size_t ws_size,
                              hipStream_t stream) {
    const int*   A  = (const int*)d_in[0];
    const float* X  = (const float*)d_in[1];
    const float* Ws = (const float*)d_in[2];
    const float* a  = (const float*)d_in[3];
    float* out = (float*)d_out;

    char* ws = (char*)d_ws;
    // Layout (~67.5 MB):
    //   [0, 2M)        WhT bf16 [d][srcrow]
    //   [2M, +32K)     C1
    //   [+32K, +64K)   C1s
    //   [+64K, +128K)  E2 (float2)
    //   [3M, 67M)      Hp (16 split-K partials, 4MB each)
    //   [67M, +512K)   Lp (16 partials, 32KB each)
    ushort* WhT = (ushort*)(ws);
    float*  C1  = (float*)(ws + (2u << 20));
    float*  C1s = (float*)(ws + (2u << 20) + (32u << 10));
    float2* E2  = (float2*)(ws + (2u << 20) + (64u << 10));
    float*  Hp  = (float*)(ws + (3u << 20));
    float*  Lp  = (float*)(ws + (67u << 20));

    k12_gemm<<<256, 256, 0, stream>>>(X, Ws, a, WhT, C1, C1s, E2);
    k3_main<<<dim3(32, 16), 512, 0, stream>>>(A, WhT, C1, C1s, E2, Hp, Lp);
    k4_final<<<1024, 256, 0, stream>>>(Hp, Lp, out);
}

// Round 8
// 411.106 us; speedup vs baseline: 1.0024x; 1.0024x over previous
//
#include <hip/hip_runtime.h>
#include <hip/hip_bf16.h>

#define NN 8192
#define DD 128

typedef __attribute__((ext_vector_type(8))) short short8;
typedef __attribute__((ext_vector_type(4))) float f32x4;
typedef unsigned int u32;
typedef unsigned long long u64;

__device__ __forceinline__ ushort f2bf(float f) {
    __hip_bfloat16 h = __float2bfloat16(f);
    return *(ushort*)&h;
}

// async 16B/lane global->LDS; LDS dest must be wave-uniform base + lane*16.
__device__ __forceinline__ void async_ld16(const void* g, void* l) {
    __builtin_amdgcn_global_load_lds(
        (const __attribute__((address_space(1))) u32*)g,
        (__attribute__((address_space(3))) u32*)l, 16, 0, 0);
}

// ---------------- K12: Wh = X @ Ws fused with per-row scalars + bf16 transpose ----
// 256 blocks x 256 thr; 32 rows/block; 4x4 register tile per thread.
__global__ __launch_bounds__(256) void k12_gemm(const float* __restrict__ X,
                                                const float* __restrict__ Ws,
                                                const float* __restrict__ a,
                                                ushort* __restrict__ WhT,
                                                float* __restrict__ C1,
                                                float* __restrict__ C1s,
                                                float2* __restrict__ E2) {
    __shared__ float lWs[128 * 132];   // [k][c] pad 132
    __shared__ float lX[32 * 132];     // [r][c] pad 132
    __shared__ ushort lT2[128 * 32];   // [c][r] bf16 transpose staging
    __shared__ float la[256];
    int t = threadIdx.x, bx = blockIdx.x;
    la[t] = a[t];
    const float4* Ws4 = (const float4*)Ws;
    const float4* X4 = (const float4*)X;
    for (int j = 0; j < 16; ++j) {
        int u = j * 256 + t;           // 0..4095 float4s of Ws
        int k = u >> 5, c4 = u & 31;
        *(float4*)&lWs[k * 132 + c4 * 4] = Ws4[u];
    }
    for (int j = 0; j < 4; ++j) {
        int u = j * 256 + t;           // 0..1023 float4s of X tile
        int r = u >> 5, c4 = u & 31;
        *(float4*)&lX[r * 132 + c4 * 4] = X4[bx * 1024 + u];
    }
    __syncthreads();
    int r0 = (t >> 5) * 4, c0 = (t & 31) * 4;
    float acc[4][4];
#pragma unroll
    for (int i = 0; i < 4; ++i)
#pragma unroll
        for (int j = 0; j < 4; ++j) acc[i][j] = 0.f;
#pragma unroll 4
    for (int k = 0; k < 128; ++k) {
        float4 wv = *(const float4*)&lWs[k * 132 + c0];
        float x0 = lX[(r0 + 0) * 132 + k];
        float x1 = lX[(r0 + 1) * 132 + k];
        float x2 = lX[(r0 + 2) * 132 + k];
        float x3 = lX[(r0 + 3) * 132 + k];
#pragma unroll
        for (int j = 0; j < 4; ++j) {
            acc[0][j] += x0 * ((const float*)&wv)[j];
            acc[1][j] += x1 * ((const float*)&wv)[j];
            acc[2][j] += x2 * ((const float*)&wv)[j];
            acc[3][j] += x3 * ((const float*)&wv)[j];
        }
    }
    // bf16 transpose staging
#pragma unroll
    for (int i = 0; i < 4; ++i)
#pragma unroll
        for (int j = 0; j < 4; ++j)
            lT2[(c0 + j) * 32 + r0 + i] = f2bf(acc[i][j]);
    // per-row scalars: s1 = Wh[r].a1, s2 = Wh[r].a2
    float p1[4], p2[4];
#pragma unroll
    for (int i = 0; i < 4; ++i) {
        p1[i] = 0.f; p2[i] = 0.f;
#pragma unroll
        for (int j = 0; j < 4; ++j) {
            p1[i] += acc[i][j] * la[c0 + j];
            p2[i] += acc[i][j] * la[128 + c0 + j];
        }
    }
#pragma unroll
    for (int m = 1; m < 32; m <<= 1) {
#pragma unroll
        for (int i = 0; i < 4; ++i) {
            p1[i] += __shfl_xor(p1[i], m);
            p2[i] += __shfl_xor(p2[i], m);
        }
    }
    if ((t & 31) == 0) {
#pragma unroll
        for (int i = 0; i < 4; ++i) {
            int row = bx * 32 + r0 + i;
            C1[row]  = __expf(p1[i]);
            C1s[row] = __expf(0.2f * p1[i]);
            E2[row]  = make_float2(__expf(p2[i]), __expf(0.2f * p2[i]));
        }
    }
    __syncthreads();
    // WhT[d][srcrow]: thread t -> d=t>>1, half=t&1; 32B contiguous
    {
        int d = t >> 1, hf = t & 1;
        uint4* dst = (uint4*)&WhT[(size_t)d * NN + bx * 32 + hf * 16];
        const uint4* src = (const uint4*)&lT2[d * 32 + hf * 16];
        dst[0] = src[0];
        dst[1] = src[1];
    }
}

// ---------------- K3: masked-softmax GEMM, row-linear A stream + ballot masks ----
// grid (32 rowblocks, 16 ksplit) x 512 thr (8 waves x 32 rows = 256 rows/block).
// Prologue per wave: stream its OWN 32 A-rows fully row-linearly (2 KB
// contiguous per row -- the DRAM-friendly k0 pattern), __ballot each 64-col
// chunk to a 64-bit mask, store to an 18 KB LDS mask table. B-slice (128 KB)
// + E-slice (4 KB) DMA'd once. ONE barrier. The kt-loop then has ZERO global
// loads and ZERO barriers: masks via conflict-free ds_read_b64 (same wave
// wrote them), B/E resident in LDS, MFMA accumulate.
// Row sums via MFMA against all-ones B. Split-K partials; NO atomics.
#define MROW 72   // mask row stride (bytes): 64B bits + 8B pad, bank-spread

__global__ __launch_bounds__(512, 2) void k3_main(
    const int* __restrict__ A, const ushort* __restrict__ WhT,
    const float* __restrict__ C1, const float* __restrict__ C1s,
    const float2* __restrict__ E2,
    float* __restrict__ Hp, float* __restrict__ Lp) {

    __shared__ __align__(16) char lB[131072];      // [p = kt*16+tp*8+c][lane*16]
    __shared__ __align__(16) char lE[4096];        // float2 E for 512 k
    __shared__ __align__(16) char lM[256 * MROW];  // [local row][8 x u64 masks]

    int tid = threadIdx.x;
    int lane = tid & 63;
    int w = tid >> 6;           // 8 waves
    int n = lane & 15;
    int kg = lane >> 4;

    int bx = blockIdx.x;        // 32 row-blocks (256 rows each)
    int kb = blockIdx.y;        // 16 k-splits (512 k each)
    int rb = bx * 256 + w * 32; // wave's 32 rows (two 16-row groups)

    float c1_0 = C1[rb + n],      c1s_0 = C1s[rb + n];
    float c1_1 = C1[rb + 16 + n], c1s_1 = C1s[rb + 16 + n];

    // stage ENTIRE B-slice (128 fragments x 1 KB) -- wave w stages p = w+8i.
    // Issued FIRST: L3-hot, lands long before the A-stream finishes.
#pragma unroll
    for (int i = 0; i < 16; ++i) {
        int p = w + i * 8;
        int kt = p >> 4, tp = (p >> 3) & 1, c = p & 7;
        const ushort* src = WhT + (size_t)(c * 16 + n) * NN +
                            (size_t)kb * 512 + kt * 64 + tp * 32 + kg * 8;
        async_ld16(src, lB + p * 1024 + lane * 16);
    }
    if (w == 0)
#pragma unroll
        for (int i = 0; i < 4; ++i)
            async_ld16((const char*)(E2 + (size_t)kb * 512) + (i * 64 + lane) * 16,
                       lE + (i * 64 + lane) * 16);

    // A-stream: wave w reads block-local rows 32w..32w+31, row-linear
    // (8 x 256 B chunks back-to-back = 2 KB contiguous per row).
    {
        const int* pA = A + (size_t)(rb) * NN + (size_t)kb * 512 + lane;
        for (int r8 = 0; r8 < 32; ++r8) {
            const int* rp = pA + (size_t)r8 * NN;
            int v[8];
#pragma unroll
            for (int c = 0; c < 8; ++c)
                v[c] = __builtin_nontemporal_load(rp + c * 64);
#pragma unroll
            for (int c = 0; c < 8; ++c) {
                u64 m = __ballot(v[c] != 0);
                if (lane == 0)
                    *(u64*)(lM + (w * 32 + r8) * MROW + c * 8) = m;
            }
        }
    }

    short8 ones;
#pragma unroll
    for (int j = 0; j < 8; ++j) ones[j] = (short)0x3F80;  // bf16 1.0

    f32x4 acc0[8], acc1[8];
#pragma unroll
    for (int c = 0; c < 8; ++c) {
        acc0[c] = (f32x4){0.f, 0.f, 0.f, 0.f};
        acc1[c] = (f32x4){0.f, 0.f, 0.f, 0.f};
    }
    f32x4 accl0 = (f32x4){0.f, 0.f, 0.f, 0.f};
    f32x4 accl1 = (f32x4){0.f, 0.f, 0.f, 0.f};

    __syncthreads();   // the ONLY barrier: B/E resident; masks are same-wave

    const char* mrow0 = lM + (w * 32 + n) * MROW;        // row-group 0
    const char* mrow1 = lM + (w * 32 + 16 + n) * MROW;   // row-group 1

    for (int kt = 0; kt < 8; ++kt) {   // 8 x 64-k tiles, NO barriers, NO global
        uint2 m0 = *(const uint2*)(mrow0 + kt * 8);   // grp0: {tp0 dword, tp1 dword}
        uint2 m1 = *(const uint2*)(mrow1 + kt * 8);   // grp1
#pragma unroll
        for (int tp = 0; tp < 2; ++tp) {
            // 8 (ep,en) pairs for this lane's 8 k-slots (broadcast across n)
            const float4* ev = (const float4*)((const float*)lE +
                                               (kt * 64 + tp * 32 + kg * 8) * 2);
            float pe[16];
            *(float4*)(pe + 0)  = ev[0];
            *(float4*)(pe + 4)  = ev[1];
            *(float4*)(pe + 8)  = ev[2];
            *(float4*)(pe + 12) = ev[3];
            u32 ab0 = ((tp ? m0.y : m0.x) >> (kg * 8)) & 0xffu;
            u32 ab1 = ((tp ? m1.y : m1.x) >> (kg * 8)) & 0xffu;
            short8 af0, af1;
#pragma unroll
            for (int u = 0; u < 8; ++u) {
                // exp(leaky(s1+s2)) = max(e^s1 e^s2, e^.2s1 e^.2s2)
                float w0 = fmaxf(c1_0 * pe[2 * u], c1s_0 * pe[2 * u + 1]);
                float w1 = fmaxf(c1_1 * pe[2 * u], c1s_1 * pe[2 * u + 1]);
                af0[u] = ((ab0 >> u) & 1u) ? (short)f2bf(w0) : (short)0;
                af1[u] = ((ab1 >> u) & 1u) ? (short)f2bf(w1) : (short)0;
            }
            const short8* bb = (const short8*)(lB + (kt * 16 + tp * 8) * 1024);
#pragma unroll
            for (int c = 0; c < 8; ++c) {
                short8 bf = bb[c * 64 + lane];   // read ONCE, feed two MFMAs
                acc0[c] = __builtin_amdgcn_mfma_f32_16x16x32_bf16(af0, bf, acc0[c], 0, 0, 0);
                acc1[c] = __builtin_amdgcn_mfma_f32_16x16x32_bf16(af1, bf, acc1[c], 0, 0, 0);
            }
            accl0 = __builtin_amdgcn_mfma_f32_16x16x32_bf16(af0, ones, accl0, 0, 0, 0);
            accl1 = __builtin_amdgcn_mfma_f32_16x16x32_bf16(af1, ones, accl1, 0, 0, 0);
        }
    }

    // epilogue. C/D layout: col = lane&15, row = (lane>>4)*4 + reg  [m89]
    float* Hpb = Hp + (size_t)kb * (NN * DD);
#pragma unroll
    for (int c = 0; c < 8; ++c)
#pragma unroll
        for (int r = 0; r < 4; ++r) {
            Hpb[(size_t)(rb + kg * 4 + r) * DD + c * 16 + n]      = acc0[c][r];
            Hpb[(size_t)(rb + 16 + kg * 4 + r) * DD + c * 16 + n] = acc1[c][r];
        }
    if (n == 0) {
        float* Lpb = Lp + (size_t)kb * NN;
#pragma unroll
        for (int r = 0; r < 4; ++r) {
            Lpb[rb + kg * 4 + r]      = accl0[r];
            Lpb[rb + 16 + kg * 4 + r] = accl1[r];
        }
    }
}

// ---------------- K4: combine split-K partials, normalize (float4) ----------------
// 262144 float4s total: 1024 blocks x 256 thr.
__global__ void k4_final(const float* __restrict__ Hp, const float* __restrict__ Lp,
                         float* __restrict__ out) {
    int g = blockIdx.x * 256 + threadIdx.x;   // 0..262143 float4s
    int i = g >> 5;                            // row (128 f / 4 = 32 f4 per row)
    float4 sv = make_float4(0.f, 0.f, 0.f, 0.f);
    float l = 0.f;
#pragma unroll
    for (int kb = 0; kb < 16; ++kb) {
        float4 v = *(const float4*)(Hp + (size_t)kb * (NN * DD) + (size_t)g * 4);
        sv.x += v.x; sv.y += v.y; sv.z += v.z; sv.w += v.w;
        l += Lp[(size_t)kb * NN + i];
    }
    float r = 1.f / l;
    *(float4*)(out + (size_t)g * 4) = make_float4(sv.x * r, sv.y * r, sv.z * r, sv.w * r);
}

extern "C" void kernel_launch(void* const* d_in, const int* in_sizes, int n_in,
                              void* d_out, int out_size, void* d_ws, size_t ws_size,
                              hipStream_t stream) {
    const int*   A  = (const int*)d_in[0];
    const float* X  = (const float*)d_in[1];
    const float* Ws = (const float*)d_in[2];
    const float* a  = (const float*)d_in[3];
    float* out = (float*)d_out;

    char* ws = (char*)d_ws;
    // Layout (~67.5 MB):
    //   [0, 2M)        WhT bf16 [d][srcrow]
    //   [2M, +32K)     C1
    //   [+32K, +64K)   C1s
    //   [+64K, +128K)  E2 (float2)
    //   [3M, 67M)      Hp (16 split-K partials, 4MB each)
    //   [67M, +512K)   Lp (16 partials, 32KB each)
    ushort* WhT = (ushort*)(ws);
    float*  C1  = (float*)(ws + (2u << 20));
    float*  C1s = (float*)(ws + (2u << 20) + (32u << 10));
    float2* E2  = (float2*)(ws + (2u << 20) + (64u << 10));
    float*  Hp  = (float*)(ws + (3u << 20));
    float*  Lp  = (float*)(ws + (67u << 20));

    k12_gemm<<<256, 256, 0, stream>>>(X, Ws, a, WhT, C1, C1s, E2);
    k3_main<<<dim3(32, 16), 512, 0, stream>>>(A, WhT, C1, C1s, E2, Hp, Lp);
    k4_final<<<1024, 256, 0, stream>>>(Hp, Lp, out);
}